// Round 1
// baseline (458.052 us; speedup 1.0000x reference)
//
#include <hip/hip_runtime.h>
#include <stdint.h>

typedef unsigned short u16;

#define MTOK 4096
#define CIN  3072
#define COUT 3072
#define GS   64
#define NG   (CIN/GS)   // 48
#define RANK 32
#define KW   3136       // CIN + RANK + 32 zero-pad = 49*64
#define KT   (KW/64)    // 49

// Workspace layout (needs (4096+3072)*3136*2 = ~45 MB):
//   xdq: (MTOK, KW) bf16  -- [0..3071]=quantized acts, [3072..3103]=lora_act, [3104..3135]=0
//   wdq: (COUT, KW) bf16  -- [0..3071]=dequant weights, [3072..3103]=proj_up,  [3104..3135]=0

typedef __attribute__((ext_vector_type(8))) short bf16x8;
typedef __attribute__((ext_vector_type(4))) float f32x4;

__device__ __forceinline__ u16 f2bf(float f) {
  union { float f; unsigned u; } v; v.f = f;
  unsigned r = v.u + 0x7FFFu + ((v.u >> 16) & 1u);  // RNE
  return (u16)(r >> 16);
}

__device__ __forceinline__ void gload_lds16(const void* g, void* l) {
  __builtin_amdgcn_global_load_lds(
      (const __attribute__((address_space(1))) unsigned int*)g,
      (__attribute__((address_space(3))) unsigned int*)l, 16, 0, 0);
}

// Kernel 1: per-token smoothing + group quant + lora_act (K-extension columns).
// One wave per row; 4 rows per block.
__global__ __launch_bounds__(256) void quant_lora_kernel(
    const float* __restrict__ x, const float* __restrict__ smooth,
    const float* __restrict__ pd, u16* __restrict__ xdq)
{
  const int wave = threadIdx.x >> 6;
  const int lane = threadIdx.x & 63;
  const int m = blockIdx.x * 4 + wave;
  const float* xr = x + (size_t)m * CIN;
  u16* orow = xdq + (size_t)m * KW;
  float acc[RANK];
#pragma unroll
  for (int r = 0; r < RANK; ++r) acc[r] = 0.f;
  for (int g = 0; g < NG; ++g) {
    const int c = g * GS + lane;
    const float xs = xr[c] / smooth[c];
    float a = fabsf(xs);
#pragma unroll
    for (int off = 32; off > 0; off >>= 1) a = fmaxf(a, __shfl_xor(a, off));
    const float ascale = a / 7.0f;                    // exact match to ref (fp32 div)
    const float qd = fmaxf(ascale, 1e-8f);
    float q = rintf(xs / qd);                         // jnp.round = RNE
    q = fminf(fmaxf(q, -8.f), 7.f);
    orow[c] = f2bf(q * ascale);
    // lora partial: acc[r] += xs * pd[c][r]
    const float4* pr = (const float4*)(pd + (size_t)c * RANK);
#pragma unroll
    for (int r4 = 0; r4 < RANK/4; ++r4) {
      const float4 p = pr[r4];
      acc[r4*4+0] += xs * p.x;
      acc[r4*4+1] += xs * p.y;
      acc[r4*4+2] += xs * p.z;
      acc[r4*4+3] += xs * p.w;
    }
  }
  // reduce lora partials across the wave
#pragma unroll
  for (int r = 0; r < RANK; ++r) {
    float v = acc[r];
#pragma unroll
    for (int off = 32; off > 0; off >>= 1) v += __shfl_xor(v, off);
    acc[r] = v;
  }
  if (lane == 0) {
#pragma unroll
    for (int r = 0; r < RANK; ++r) orow[CIN + r] = f2bf(acc[r]);
  } else if (lane >= 32) {
    orow[CIN + RANK + (lane - 32)] = 0;  // zero pad (bf16 0 = 0x0000)
  }
}

// Kernel 2: weight dequant to bf16 + proj_up append + zero pad. One block per out-channel.
__global__ __launch_bounds__(256) void wdq_kernel(
    const int* __restrict__ qw, const float* __restrict__ wsc,
    const float* __restrict__ pu, u16* __restrict__ wdq)
{
  const int o = blockIdx.x;
  const int t = threadIdx.x;
  const int4* qrow = (const int4*)(qw + (size_t)o * CIN);
  u16* orow = wdq + (size_t)o * KW;
#pragma unroll
  for (int p = 0; p < 3; ++p) {
    const int c4 = p * 256 + t;            // 4-element chunk index, c = c4*4
    const int g = (c4 * 4) >> 6;
    const float ws = wsc[g * COUT + o];    // wscales is (G, C_out)
    const int4 qv = qrow[c4];
    ushort4 ov;
    ov.x = f2bf((float)(qv.x - 8) * ws);
    ov.y = f2bf((float)(qv.y - 8) * ws);
    ov.z = f2bf((float)(qv.z - 8) * ws);
    ov.w = f2bf((float)(qv.w - 8) * ws);
    ((ushort4*)orow)[c4] = ov;
  }
  if (t < RANK)      orow[CIN + t] = f2bf(pu[(size_t)o * RANK + t]);
  else if (t < 64)   orow[CIN + t] = 0;
}

// Kernel 3: m97-style 128x128 bf16 MFMA GEMM, K=3136 (lora folded in), +bias epilogue.
// NT layout: A=(M,K) row-major, B=(N,K) row-major, both k-contiguous.
__global__ __launch_bounds__(256) void gemm_kernel(
    const u16* __restrict__ xdq, const u16* __restrict__ wdq,
    const float* __restrict__ bias, float* __restrict__ out)
{
  __shared__ __align__(16) u16 sA[128 * 64];
  __shared__ __align__(16) u16 sB[128 * 64];
  const int t = threadIdx.x;
  const int wave = t >> 6, lane = t & 63;
  const int wm = wave >> 1, wn = wave & 1;           // 2x2 wave grid, 64x64 each
  const int m0 = blockIdx.y * 128, n0 = blockIdx.x * 128;
  const int lrow = lane >> 3;                        // 0..7 row within 8-row chunk
  const int lcol = (lane & 7) * 8;                   // element col within 64

  f32x4 acc[4][4];
  const f32x4 fz = {0.f, 0.f, 0.f, 0.f};
#pragma unroll
  for (int i = 0; i < 4; ++i)
#pragma unroll
    for (int j = 0; j < 4; ++j) acc[i][j] = fz;

  const int lm = lane & 15;
  const int lkq = (lane >> 4) * 8;

  for (int kt = 0; kt < KT; ++kt) {
    const u16* Ab = xdq + (size_t)m0 * KW + kt * 64;
    const u16* Bb = wdq + (size_t)n0 * KW + kt * 64;
#pragma unroll
    for (int r = 0; r < 4; ++r) {
      const int ci = wave * 4 + r;                   // 1KB chunk id (16 per tile)
      const int row = ci * 8 + lrow;
      gload_lds16(Ab + (size_t)row * KW + lcol, &sA[ci * 512 + lane * 8]);
      gload_lds16(Bb + (size_t)row * KW + lcol, &sB[ci * 512 + lane * 8]);
    }
    __syncthreads();   // drains vmcnt incl. global_load_lds
#pragma unroll
    for (int kk = 0; kk < 2; ++kk) {
      const int ko = kk * 32 + lkq;
      bf16x8 af[4], bfr[4];
#pragma unroll
      for (int i = 0; i < 4; ++i)
        af[i] = *(const bf16x8*)&sA[(wm * 64 + i * 16 + lm) * 64 + ko];
#pragma unroll
      for (int j = 0; j < 4; ++j)
        bfr[j] = *(const bf16x8*)&sB[(wn * 64 + j * 16 + lm) * 64 + ko];
#pragma unroll
      for (int i = 0; i < 4; ++i)
#pragma unroll
        for (int j = 0; j < 4; ++j)
          acc[i][j] = __builtin_amdgcn_mfma_f32_16x16x32_bf16(af[i], bfr[j], acc[i][j], 0, 0, 0);
    }
    __syncthreads();
  }

  // epilogue: C/D layout col=lane&15, row=(lane>>4)*4+reg  [m89-verified]
#pragma unroll
  for (int j = 0; j < 4; ++j) {
    const int col = n0 + wn * 64 + j * 16 + lm;
    const float bv = bias[col];
#pragma unroll
    for (int i = 0; i < 4; ++i) {
      const int row0 = m0 + wm * 64 + i * 16 + (lane >> 4) * 4;
#pragma unroll
      for (int r = 0; r < 4; ++r)
        out[(size_t)(row0 + r) * COUT + col] = acc[i][j][r] + bv;
    }
  }
}

extern "C" void kernel_launch(void* const* d_in, const int* in_sizes, int n_in,
                              void* d_out, int out_size, void* d_ws, size_t ws_size,
                              hipStream_t stream) {
  const float* x      = (const float*)d_in[0];
  const int*   qw     = (const int*)d_in[1];
  const float* wsc    = (const float*)d_in[2];
  const float* smooth = (const float*)d_in[3];
  const float* pd     = (const float*)d_in[4];
  const float* pu     = (const float*)d_in[5];
  const float* bias   = (const float*)d_in[6];
  float* out = (float*)d_out;

  u16* xdq = (u16*)d_ws;                       // 4096*3136*2 = 25.7 MB
  u16* wdq = xdq + (size_t)MTOK * KW;          // 3072*3136*2 = 19.3 MB

  quant_lora_kernel<<<MTOK / 4, 256, 0, stream>>>(x, smooth, pd, xdq);
  wdq_kernel<<<COUT, 256, 0, stream>>>(qw, wsc, pu, wdq);
  gemm_kernel<<<dim3(COUT / 128, MTOK / 128), 256, 0, stream>>>(xdq, wdq, bias, out);
}

// Round 2
// 326.368 us; speedup vs baseline: 1.4035x; 1.4035x over previous
//
#include <hip/hip_runtime.h>
#include <stdint.h>

typedef unsigned short u16;

#define MTOK 4096
#define CIN  3072
#define COUT 3072
#define GS   64
#define RANK 32
#define KW   3136       // CIN + RANK + 32 zero-pad = 49*64
#define KT   (KW/64)    // 49
#define LKSPLIT 4
#define LKC (CIN/LKSPLIT)   // 768

// Workspace layout:
//   xdq:  (MTOK, KW) bf16   -- [0..3071]=quant acts, [3072..3103]=lora_act, [3104..3135]=0
//   wdq:  (COUT, KW) bf16   -- [0..3071]=dequant weights, [3072..3103]=proj_up, [3104..3135]=0
//   lp:   (LKSPLIT, MTOK, RANK) f32 -- lora K-split partials (deterministic, no atomics)

typedef __attribute__((ext_vector_type(8))) short bf16x8;
typedef __attribute__((ext_vector_type(4))) float f32x4;

__device__ __forceinline__ u16 f2bf(float f) {
  union { float f; unsigned u; } v; v.f = f;
  unsigned r = v.u + 0x7FFFu + ((v.u >> 16) & 1u);  // RNE
  return (u16)(r >> 16);
}

__device__ __forceinline__ void gload_lds16(const void* g, void* l) {
  __builtin_amdgcn_global_load_lds(
      (const __attribute__((address_space(1))) unsigned int*)g,
      (__attribute__((address_space(3))) unsigned int*)l, 16, 0, 0);
}

__device__ __forceinline__ float quant1(float xs, float ascale, float qd) {
  float q = rintf(xs / qd);                      // jnp.round = RNE
  q = fminf(fmaxf(q, -8.f), 7.f);
  return q * ascale;
}

// Kernel 1: streaming smoothing + per-group int4 quant. float4/thread;
// 16 lanes x 4 elems = one 64-group -> amax via 4 shfl_xor within subgroup.
__global__ __launch_bounds__(256) void quant_kernel(
    const float* __restrict__ x, const float* __restrict__ smooth,
    u16* __restrict__ xdq)
{
  const int b = blockIdx.x;            // 12288 blocks = 4096 rows * 3 parts
  const int m = b / 3;
  const int part = b - m * 3;
  const int c0 = part * 1024 + threadIdx.x * 4;
  const float4 xv = *(const float4*)(x + (size_t)m * CIN + c0);
  const float4 sv = *(const float4*)(smooth + c0);
  const float xs0 = xv.x / sv.x, xs1 = xv.y / sv.y;
  const float xs2 = xv.z / sv.z, xs3 = xv.w / sv.w;
  float a = fmaxf(fmaxf(fabsf(xs0), fabsf(xs1)), fmaxf(fabsf(xs2), fabsf(xs3)));
#pragma unroll
  for (int off = 1; off < 16; off <<= 1) a = fmaxf(a, __shfl_xor(a, off));
  const float ascale = a / 7.0f;
  const float qd = fmaxf(ascale, 1e-8f);
  ushort4 o;
  o.x = f2bf(quant1(xs0, ascale, qd));
  o.y = f2bf(quant1(xs1, ascale, qd));
  o.z = f2bf(quant1(xs2, ascale, qd));
  o.w = f2bf(quant1(xs3, ascale, qd));
  *(ushort4*)(xdq + (size_t)m * KW + c0) = o;
}

// Kernel 2: weight dequant to bf16 + proj_up append + zero pad. One block per out-channel.
__global__ __launch_bounds__(256) void wdq_kernel(
    const int* __restrict__ qw, const float* __restrict__ wsc,
    const float* __restrict__ pu, u16* __restrict__ wdq)
{
  const int o = blockIdx.x;
  const int t = threadIdx.x;
  const int4* qrow = (const int4*)(qw + (size_t)o * CIN);
  u16* orow = wdq + (size_t)o * KW;
#pragma unroll
  for (int p = 0; p < 3; ++p) {
    const int c4 = p * 256 + t;            // 4-element chunk index
    const int g = (c4 * 4) >> 6;
    const float ws = wsc[g * COUT + o];    // wscales is (G, C_out)
    const int4 qv = qrow[c4];
    ushort4 ov;
    ov.x = f2bf((float)(qv.x - 8) * ws);
    ov.y = f2bf((float)(qv.y - 8) * ws);
    ov.z = f2bf((float)(qv.z - 8) * ws);
    ov.w = f2bf((float)(qv.w - 8) * ws);
    ((ushort4*)orow)[c4] = ov;
  }
  if (t < RANK)      orow[CIN + t] = f2bf(pu[(size_t)o * RANK + t]);
  else if (t < 64)   orow[CIN + t] = 0;
}

// Kernel 3: lora_act = xs . pd as small MFMA GEMM, K-split into partials.
// A (128 x 64k tile) built on the fly from x/smooth; B tile transposed from pd.
__global__ __launch_bounds__(256) void lora_gemm_kernel(
    const float* __restrict__ x, const float* __restrict__ smooth,
    const float* __restrict__ pd, float* __restrict__ lp)
{
  __shared__ __align__(16) u16 sA[128 * 64];
  __shared__ __align__(16) u16 sB[32 * 64];
  const int m0 = blockIdx.x * 128;
  const int kblk = blockIdx.y;
  const int t = threadIdx.x, wave = t >> 6, lane = t & 63;
  const int lm = lane & 15, lkq = (lane >> 4) * 8;

  f32x4 acc[2][2];
  const f32x4 fz = {0.f, 0.f, 0.f, 0.f};
#pragma unroll
  for (int i = 0; i < 2; ++i)
#pragma unroll
    for (int j = 0; j < 2; ++j) acc[i][j] = fz;

  for (int kt = 0; kt < LKC / 64; ++kt) {
    const int k0 = kblk * LKC + kt * 64;
    // stage A: 128 rows x 64 k, fp32 -> bf16 (smoothing fused)
#pragma unroll
    for (int it = 0; it < 8; ++it) {
      const int row = it * 16 + (t >> 4);
      const int col = (t & 15) * 4;
      const float4 xv = *(const float4*)(x + (size_t)(m0 + row) * CIN + k0 + col);
      const float4 sv = *(const float4*)(smooth + k0 + col);
      ushort4 ov;
      ov.x = f2bf(xv.x / sv.x);
      ov.y = f2bf(xv.y / sv.y);
      ov.z = f2bf(xv.z / sv.z);
      ov.w = f2bf(xv.w / sv.w);
      *(ushort4*)&sA[row * 64 + col] = ov;
    }
    // stage B: transpose pd[k][r] -> sB[r*64+k], 64k x 32r
#pragma unroll
    for (int i = 0; i < 8; ++i) {
      const int idx = i * 256 + t;
      const int k = idx >> 5, r = idx & 31;
      sB[r * 64 + k] = f2bf(pd[(size_t)(k0 + k) * RANK + r]);
    }
    __syncthreads();
#pragma unroll
    for (int kk = 0; kk < 2; ++kk) {
      const int ko = kk * 32 + lkq;
      bf16x8 af[2], bfr[2];
#pragma unroll
      for (int i = 0; i < 2; ++i)
        af[i] = *(const bf16x8*)&sA[(wave * 32 + i * 16 + lm) * 64 + ko];
#pragma unroll
      for (int j = 0; j < 2; ++j)
        bfr[j] = *(const bf16x8*)&sB[(j * 16 + lm) * 64 + ko];
#pragma unroll
      for (int i = 0; i < 2; ++i)
#pragma unroll
        for (int j = 0; j < 2; ++j)
          acc[i][j] = __builtin_amdgcn_mfma_f32_16x16x32_bf16(af[i], bfr[j], acc[i][j], 0, 0, 0);
    }
    __syncthreads();
  }
  // write deterministic K-split partial
  float* lpk = lp + (size_t)kblk * MTOK * RANK;
#pragma unroll
  for (int i = 0; i < 2; ++i)
#pragma unroll
    for (int j = 0; j < 2; ++j) {
      const int col = j * 16 + lm;
      const int row0 = m0 + wave * 32 + i * 16 + (lane >> 4) * 4;
#pragma unroll
      for (int r = 0; r < 4; ++r)
        lpk[(size_t)(row0 + r) * RANK + col] = acc[i][j][r];
    }
}

// Kernel 4: sum lora partials -> bf16 K-extension columns of xdq (+ zero pad).
__global__ __launch_bounds__(256) void lora_fix_kernel(
    const float* __restrict__ lp, u16* __restrict__ xdq)
{
  const int idx = blockIdx.x * 256 + threadIdx.x;   // 4096*64
  const int m = idx >> 6, c = idx & 63;
  u16 v = 0;
  if (c < RANK) {
    float s = 0.f;
#pragma unroll
    for (int k = 0; k < LKSPLIT; ++k) s += lp[((size_t)k * MTOK + m) * RANK + c];
    v = f2bf(s);
  }
  xdq[(size_t)m * KW + CIN + c] = v;
}

// Kernel 5: m97-style 128x128 bf16 MFMA GEMM, K=3136 (lora folded in), +bias epilogue.
__global__ __launch_bounds__(256) void gemm_kernel(
    const u16* __restrict__ xdq, const u16* __restrict__ wdq,
    const float* __restrict__ bias, float* __restrict__ out)
{
  __shared__ __align__(16) u16 sA[128 * 64];
  __shared__ __align__(16) u16 sB[128 * 64];
  const int t = threadIdx.x;
  const int wave = t >> 6, lane = t & 63;
  const int wm = wave >> 1, wn = wave & 1;           // 2x2 wave grid, 64x64 each
  const int m0 = blockIdx.y * 128, n0 = blockIdx.x * 128;
  const int lrow = lane >> 3;
  const int lcol = (lane & 7) * 8;

  f32x4 acc[4][4];
  const f32x4 fz = {0.f, 0.f, 0.f, 0.f};
#pragma unroll
  for (int i = 0; i < 4; ++i)
#pragma unroll
    for (int j = 0; j < 4; ++j) acc[i][j] = fz;

  const int lm = lane & 15;
  const int lkq = (lane >> 4) * 8;

  for (int kt = 0; kt < KT; ++kt) {
    const u16* Ab = xdq + (size_t)m0 * KW + kt * 64;
    const u16* Bb = wdq + (size_t)n0 * KW + kt * 64;
#pragma unroll
    for (int r = 0; r < 4; ++r) {
      const int ci = wave * 4 + r;
      const int row = ci * 8 + lrow;
      gload_lds16(Ab + (size_t)row * KW + lcol, &sA[ci * 512 + lane * 8]);
      gload_lds16(Bb + (size_t)row * KW + lcol, &sB[ci * 512 + lane * 8]);
    }
    __syncthreads();
#pragma unroll
    for (int kk = 0; kk < 2; ++kk) {
      const int ko = kk * 32 + lkq;
      bf16x8 af[4], bfr[4];
#pragma unroll
      for (int i = 0; i < 4; ++i)
        af[i] = *(const bf16x8*)&sA[(wm * 64 + i * 16 + lm) * 64 + ko];
#pragma unroll
      for (int j = 0; j < 4; ++j)
        bfr[j] = *(const bf16x8*)&sB[(wn * 64 + j * 16 + lm) * 64 + ko];
#pragma unroll
      for (int i = 0; i < 4; ++i)
#pragma unroll
        for (int j = 0; j < 4; ++j)
          acc[i][j] = __builtin_amdgcn_mfma_f32_16x16x32_bf16(af[i], bfr[j], acc[i][j], 0, 0, 0);
    }
    __syncthreads();
  }

#pragma unroll
  for (int j = 0; j < 4; ++j) {
    const int col = n0 + wn * 64 + j * 16 + lm;
    const float bv = bias[col];
#pragma unroll
    for (int i = 0; i < 4; ++i) {
      const int row0 = m0 + wm * 64 + i * 16 + (lane >> 4) * 4;
#pragma unroll
      for (int r = 0; r < 4; ++r)
        out[(size_t)(row0 + r) * COUT + col] = acc[i][j][r] + bv;
    }
  }
}

extern "C" void kernel_launch(void* const* d_in, const int* in_sizes, int n_in,
                              void* d_out, int out_size, void* d_ws, size_t ws_size,
                              hipStream_t stream) {
  const float* x      = (const float*)d_in[0];
  const int*   qw     = (const int*)d_in[1];
  const float* wsc    = (const float*)d_in[2];
  const float* smooth = (const float*)d_in[3];
  const float* pd     = (const float*)d_in[4];
  const float* pu     = (const float*)d_in[5];
  const float* bias   = (const float*)d_in[6];
  float* out = (float*)d_out;

  u16* xdq = (u16*)d_ws;                           // 4096*3136*2 = 25.7 MB
  u16* wdq = xdq + (size_t)MTOK * KW;              // 3072*3136*2 = 19.3 MB
  float* lp = (float*)(wdq + (size_t)COUT * KW);   // 4*4096*32*4 = 2.1 MB

  quant_kernel<<<MTOK * 3, 256, 0, stream>>>(x, smooth, xdq);
  wdq_kernel<<<COUT, 256, 0, stream>>>(qw, wsc, pu, wdq);
  lora_gemm_kernel<<<dim3(MTOK / 128, LKSPLIT), 256, 0, stream>>>(x, smooth, pd, lp);
  lora_fix_kernel<<<MTOK * 64 / 256, 256, 0, stream>>>(lp, xdq);
  gemm_kernel<<<dim3(COUT / 128, MTOK / 128), 256, 0, stream>>>(xdq, wdq, bias, out);
}

// Round 3
// 278.122 us; speedup vs baseline: 1.6469x; 1.1735x over previous
//
#include <hip/hip_runtime.h>
#include <stdint.h>

typedef unsigned short u16;

#define MTOK 4096
#define CIN  3072
#define COUT 3072
#define GS   64
#define RANK 32
#define KW   3136       // CIN + RANK + 32 zero-pad = 49*64
#define KT   (KW/64)    // 49
#define LKSPLIT 8
#define LKC (CIN/LKSPLIT)   // 384

// prep grid layout: [0,LBLK) lora, [LBLK, LBLK+QBLK) quant, rest wdq
#define LBLK (MTOK/128*LKSPLIT)   // 256
#define QBLK (MTOK*3)             // 12288
#define WBLK COUT                 // 3072

typedef __attribute__((ext_vector_type(8))) short bf16x8;
typedef __attribute__((ext_vector_type(4))) float f32x4;

__device__ __forceinline__ u16 f2bf(float f) {
  union { float f; unsigned u; } v; v.f = f;
  unsigned r = v.u + 0x7FFFu + ((v.u >> 16) & 1u);  // RNE
  return (u16)(r >> 16);
}

__device__ __forceinline__ void gload_lds16(const void* g, void* l) {
  __builtin_amdgcn_global_load_lds(
      (const __attribute__((address_space(1))) unsigned int*)g,
      (__attribute__((address_space(3))) unsigned int*)l, 16, 0, 0);
}

__device__ __forceinline__ float quant1(float xs, float ascale, float qd) {
  float q = rintf(xs / qd);                      // jnp.round = RNE
  q = fminf(fmaxf(q, -8.f), 7.f);
  return q * ascale;
}

// Fused prep: lora partial GEMM blocks + activation quant blocks + weight dequant blocks.
__global__ __launch_bounds__(256) void prep_kernel(
    const float* __restrict__ x, const float* __restrict__ smooth,
    const int* __restrict__ qw, const float* __restrict__ wsc,
    const float* __restrict__ pd, const float* __restrict__ pu,
    u16* __restrict__ xdq, u16* __restrict__ wdq, float* __restrict__ lp)
{
  const int b = blockIdx.x;
  const int t = threadIdx.x;

  if (b < LBLK) {
    // ---- lora partial: lora_act[m0..m0+128) for K-chunk kblk ----
    __shared__ __align__(16) u16 sA[128 * 64];
    __shared__ __align__(16) u16 sB[32 * 64];
    const int m0 = (b >> 3) * 128;        // 32 m-blocks
    const int kblk = b & 7;               // 8 K-splits
    const int wave = t >> 6, lane = t & 63;
    const int lm = lane & 15, lkq = (lane >> 4) * 8;

    f32x4 acc[2][2];
    const f32x4 fz = {0.f, 0.f, 0.f, 0.f};
#pragma unroll
    for (int i = 0; i < 2; ++i)
#pragma unroll
      for (int j = 0; j < 2; ++j) acc[i][j] = fz;

    for (int kt = 0; kt < LKC / 64; ++kt) {
      const int k0 = kblk * LKC + kt * 64;
#pragma unroll
      for (int it = 0; it < 8; ++it) {
        const int row = it * 16 + (t >> 4);
        const int col = (t & 15) * 4;
        const float4 xv = *(const float4*)(x + (size_t)(m0 + row) * CIN + k0 + col);
        const float4 sv = *(const float4*)(smooth + k0 + col);
        ushort4 ov;
        ov.x = f2bf(xv.x / sv.x);
        ov.y = f2bf(xv.y / sv.y);
        ov.z = f2bf(xv.z / sv.z);
        ov.w = f2bf(xv.w / sv.w);
        *(ushort4*)&sA[row * 64 + col] = ov;
      }
#pragma unroll
      for (int i = 0; i < 8; ++i) {
        const int idx = i * 256 + t;
        const int k = idx >> 5, r = idx & 31;
        sB[r * 64 + k] = f2bf(pd[(size_t)(k0 + k) * RANK + r]);
      }
      __syncthreads();
#pragma unroll
      for (int kk = 0; kk < 2; ++kk) {
        const int ko = kk * 32 + lkq;
        bf16x8 af[2], bfr[2];
#pragma unroll
        for (int i = 0; i < 2; ++i)
          af[i] = *(const bf16x8*)&sA[(wave * 32 + i * 16 + lm) * 64 + ko];
#pragma unroll
        for (int j = 0; j < 2; ++j)
          bfr[j] = *(const bf16x8*)&sB[(j * 16 + lm) * 64 + ko];
#pragma unroll
        for (int i = 0; i < 2; ++i)
#pragma unroll
          for (int j = 0; j < 2; ++j)
            acc[i][j] = __builtin_amdgcn_mfma_f32_16x16x32_bf16(af[i], bfr[j], acc[i][j], 0, 0, 0);
      }
      __syncthreads();
    }
    float* lpk = lp + (size_t)kblk * MTOK * RANK;
#pragma unroll
    for (int i = 0; i < 2; ++i)
#pragma unroll
      for (int j = 0; j < 2; ++j) {
        const int col = j * 16 + lm;
        const int row0 = m0 + wave * 32 + i * 16 + (lane >> 4) * 4;
#pragma unroll
        for (int r = 0; r < 4; ++r)
          lpk[(size_t)(row0 + r) * RANK + col] = acc[i][j][r];
      }
  } else if (b < LBLK + QBLK) {
    // ---- activation quant: float4/thread, 16 lanes = one 64-group ----
    const int qb = b - LBLK;
    const int m = qb / 3;
    const int part = qb - m * 3;
    const int c0 = part * 1024 + t * 4;
    const float4 xv = *(const float4*)(x + (size_t)m * CIN + c0);
    const float4 sv = *(const float4*)(smooth + c0);
    const float xs0 = xv.x / sv.x, xs1 = xv.y / sv.y;
    const float xs2 = xv.z / sv.z, xs3 = xv.w / sv.w;
    float a = fmaxf(fmaxf(fabsf(xs0), fabsf(xs1)), fmaxf(fabsf(xs2), fabsf(xs3)));
#pragma unroll
    for (int off = 1; off < 16; off <<= 1) a = fmaxf(a, __shfl_xor(a, off));
    const float ascale = a / 7.0f;
    const float qd = fmaxf(ascale, 1e-8f);
    ushort4 o;
    o.x = f2bf(quant1(xs0, ascale, qd));
    o.y = f2bf(quant1(xs1, ascale, qd));
    o.z = f2bf(quant1(xs2, ascale, qd));
    o.w = f2bf(quant1(xs3, ascale, qd));
    *(ushort4*)(xdq + (size_t)m * KW + c0) = o;
  } else {
    // ---- weight dequant + proj_up append + zero pad ----
    const int o = b - LBLK - QBLK;
    const int4* qrow = (const int4*)(qw + (size_t)o * CIN);
    u16* orow = wdq + (size_t)o * KW;
#pragma unroll
    for (int p = 0; p < 3; ++p) {
      const int c4 = p * 256 + t;
      const int g = (c4 * 4) >> 6;
      const float ws = wsc[g * COUT + o];    // wscales is (G, C_out)
      const int4 qv = qrow[c4];
      ushort4 ov;
      ov.x = f2bf((float)(qv.x - 8) * ws);
      ov.y = f2bf((float)(qv.y - 8) * ws);
      ov.z = f2bf((float)(qv.z - 8) * ws);
      ov.w = f2bf((float)(qv.w - 8) * ws);
      ((ushort4*)orow)[c4] = ov;
    }
    if (t < RANK)      orow[CIN + t] = f2bf(pu[(size_t)o * RANK + t]);
    else if (t < 64)   orow[CIN + t] = 0;
  }
}

// Sum lora partials -> bf16 K-extension columns of xdq (+ zero pad).
__global__ __launch_bounds__(256) void lora_fix_kernel(
    const float* __restrict__ lp, u16* __restrict__ xdq)
{
  const int idx = blockIdx.x * 256 + threadIdx.x;   // 4096*64
  const int m = idx >> 6, c = idx & 63;
  u16 v = 0;
  if (c < RANK) {
    float s = 0.f;
#pragma unroll
    for (int k = 0; k < LKSPLIT; ++k) s += lp[((size_t)k * MTOK + m) * RANK + c];
    v = f2bf(s);
  }
  xdq[(size_t)m * KW + CIN + c] = v;
}

// Main GEMM: 128x128 bf16 MFMA, K=3136 (lora folded in), XOR-swizzled LDS.
// LDS layout: L[r][cb] = G[r][cb ^ (r&7)] (8-elem col blocks) -> fragment reads
// spread across all 8 bank groups instead of 16-way conflicting on one.
__global__ __launch_bounds__(256) void gemm_kernel(
    const u16* __restrict__ xdq, const u16* __restrict__ wdq,
    const float* __restrict__ bias, float* __restrict__ out)
{
  __shared__ __align__(16) u16 sA[128 * 64];
  __shared__ __align__(16) u16 sB[128 * 64];
  const int t = threadIdx.x;
  const int wave = t >> 6, lane = t & 63;
  const int wm = wave >> 1, wn = wave & 1;           // 2x2 wave grid, 64x64 each
  const int m0 = blockIdx.y * 128, n0 = blockIdx.x * 128;
  const int lrow = lane >> 3;                        // 0..7 row within 8-row chunk
  const int gcol = ((lane & 7) ^ lrow) * 8;          // swizzled global col block

  f32x4 acc[4][4];
  const f32x4 fz = {0.f, 0.f, 0.f, 0.f};
#pragma unroll
  for (int i = 0; i < 4; ++i)
#pragma unroll
    for (int j = 0; j < 4; ++j) acc[i][j] = fz;

  const int lm = lane & 15;
  const int xs7 = lm & 7;                            // row&7 for all fragment rows
  const int q4 = lane >> 4;

  for (int kt = 0; kt < KT; ++kt) {
    const u16* Ab = xdq + (size_t)m0 * KW + kt * 64;
    const u16* Bb = wdq + (size_t)n0 * KW + kt * 64;
#pragma unroll
    for (int r = 0; r < 4; ++r) {
      const int ci = wave * 4 + r;                   // 1KB chunk id (16 per tile)
      const int row = ci * 8 + lrow;
      gload_lds16(Ab + (size_t)row * KW + gcol, &sA[ci * 512 + lane * 8]);
      gload_lds16(Bb + (size_t)row * KW + gcol, &sB[ci * 512 + lane * 8]);
    }
    __syncthreads();   // drains vmcnt incl. global_load_lds
#pragma unroll
    for (int kk = 0; kk < 2; ++kk) {
      const int csw = ((kk * 4 + q4) ^ xs7) * 8;     // swizzled LDS col for this k-block
      bf16x8 af[4], bfr[4];
#pragma unroll
      for (int i = 0; i < 4; ++i)
        af[i] = *(const bf16x8*)&sA[(wm * 64 + i * 16 + lm) * 64 + csw];
#pragma unroll
      for (int j = 0; j < 4; ++j)
        bfr[j] = *(const bf16x8*)&sB[(wn * 64 + j * 16 + lm) * 64 + csw];
#pragma unroll
      for (int i = 0; i < 4; ++i)
#pragma unroll
        for (int j = 0; j < 4; ++j)
          acc[i][j] = __builtin_amdgcn_mfma_f32_16x16x32_bf16(af[i], bfr[j], acc[i][j], 0, 0, 0);
    }
    __syncthreads();
  }

  // epilogue: C/D layout col=lane&15, row=(lane>>4)*4+reg  [m89-verified]
#pragma unroll
  for (int j = 0; j < 4; ++j) {
    const int col = n0 + wn * 64 + j * 16 + lm;
    const float bv = bias[col];
#pragma unroll
    for (int i = 0; i < 4; ++i) {
      const int row0 = m0 + wm * 64 + i * 16 + (lane >> 4) * 4;
#pragma unroll
      for (int r = 0; r < 4; ++r)
        out[(size_t)(row0 + r) * COUT + col] = acc[i][j][r] + bv;
    }
  }
}

extern "C" void kernel_launch(void* const* d_in, const int* in_sizes, int n_in,
                              void* d_out, int out_size, void* d_ws, size_t ws_size,
                              hipStream_t stream) {
  const float* x      = (const float*)d_in[0];
  const int*   qw     = (const int*)d_in[1];
  const float* wsc    = (const float*)d_in[2];
  const float* smooth = (const float*)d_in[3];
  const float* pd     = (const float*)d_in[4];
  const float* pu     = (const float*)d_in[5];
  const float* bias   = (const float*)d_in[6];
  float* out = (float*)d_out;

  u16* xdq = (u16*)d_ws;                           // 4096*3136*2 = 25.7 MB
  u16* wdq = xdq + (size_t)MTOK * KW;              // 3072*3136*2 = 19.3 MB
  float* lp = (float*)(wdq + (size_t)COUT * KW);   // 8*4096*32*4 = 4.2 MB

  prep_kernel<<<LBLK + QBLK + WBLK, 256, 0, stream>>>(x, smooth, qw, wsc, pd, pu,
                                                      xdq, wdq, lp);
  lora_fix_kernel<<<MTOK * 64 / 256, 256, 0, stream>>>(lp, xdq);
  gemm_kernel<<<dim3(COUT / 128, MTOK / 128), 256, 0, stream>>>(xdq, wdq, bias, out);
}